// Round 8
// baseline (479.711 us; speedup 1.0000x reference)
//
#include <hip/hip_runtime.h>
#include <hip/hip_fp16.h>
#include <math.h>

// GCN 2-layer, CSR-gather formulation (no feature atomics).
// norm_e = dinv[src]*dinv[dst] factorizes: pre-scale rows at source (in the
// GEMM epilogue), gather-sum raw, post-scale at destination.
// R3: gemm1 LDS bank-conflict fix. R5: h1 fp16 rows padded to 64.
// R7: one-pass scatter fill was structurally stuck at 143 us (10x write amp,
// R2/R4/R5 tweaks all neutral). Replace with two-level scatter:
//   k_coarse  : 49-bin LDS histogram (kills old k_deg's 3.2M global atomics)
//   k_part    : scatter packed (src<<11|dloc) pairs into bucket regions via
//               LDS FIFOs; every global write is a contiguous chunk -> amp~1
//   k_bdeg    : per-bucket degree histogram in LDS -> degi
//   k_bucketfill: per-bucket CSR fill; window (260KB pairs + 260KB colidx +
//               8KB cursors) cache-resident; phased grid caps live windows.

constexpr int N    = 100000;
constexpr int E    = 3200000;
constexpr int F_IN = 128;
constexpr int H    = 50;
constexpr int C    = 2;
constexpr int HP   = 64;                  // padded h1 row (halves)
constexpr int NB   = (N + 1023) / 1024;   // 98 scan blocks

constexpr int BSH   = 11;                 // bucket shift: 2048 nodes/bucket
constexpr int BSZ   = 1 << BSH;
constexpr int NBUCK = (N + BSZ - 1) / BSZ;        // 49
constexpr int PART_NBLK = 256;
constexpr int EPB   = E / PART_NBLK;      // 12500 edges per partition block
constexpr int CAP   = 48;                 // FIFO capacity per bucket

constexpr int XS_LD = F_IN + 4;   // 132: (4r+k)%32 -> worst 2-way (free)
constexpr int WS_LD = 64;         // padded j-dim, 16-aligned groups

typedef int int4v __attribute__((ext_vector_type(4)));   // nt-load-compatible

// ---------------- CSR build ----------------

__global__ __launch_bounds__(256) void k_zero(int* __restrict__ degi,
                                              int* __restrict__ bcnt) {
    int i = blockIdx.x * blockDim.x + threadIdx.x;
    if (i < N) degi[i] = 0;
    if (i < NBUCK) bcnt[i] = 0;
}

// coarse 49-bin histogram via LDS
__global__ __launch_bounds__(256) void k_coarse(const int* __restrict__ dst,
                                                int* __restrict__ bcnt) {
    __shared__ int h[NBUCK];
    const int t = threadIdx.x;
    if (t < NBUCK) h[t] = 0;
    __syncthreads();
    const int4v* dst4 = (const int4v*)dst;
    long q0 = (long)blockIdx.x * (EPB / 4), q1 = q0 + EPB / 4;
    for (long q = q0 + t; q < q1; q += 256) {
        int4v d = __builtin_nontemporal_load(dst4 + q);
        atomicAdd(&h[d.x >> BSH], 1);
        atomicAdd(&h[d.y >> BSH], 1);
        atomicAdd(&h[d.z >> BSH], 1);
        atomicAdd(&h[d.w >> BSH], 1);
    }
    __syncthreads();
    if (t < NBUCK) atomicAdd(&bcnt[t], h[t]);
}

// serial scan of 49 bucket counts -> bptr, gcur
__global__ __launch_bounds__(64) void k_scan49(const int* __restrict__ bcnt,
                                               int* __restrict__ bptr,
                                               int* __restrict__ gcur) {
    if (threadIdx.x == 0) {
        int run = 0;
        for (int k = 0; k < NBUCK; ++k) {
            bptr[k] = run; gcur[k] = run; run += bcnt[k];
        }
        bptr[NBUCK] = run;   // == E
    }
}

// partition: scatter packed pairs into bucket regions, LDS FIFO staging so
// global writes are contiguous ~20-entry chunks (write amp ~1)
__global__ __launch_bounds__(256) void k_part(const int* __restrict__ src,
                                              const int* __restrict__ dst,
                                              int* __restrict__ gcur,
                                              int* __restrict__ pairs) {
    __shared__ int fifo[NBUCK][CAP];
    __shared__ int lcnt[NBUCK];
    const int t = threadIdx.x;
    if (t < NBUCK) lcnt[t] = 0;
    __syncthreads();
    const int4v* dst4 = (const int4v*)dst;
    const int4v* src4 = (const int4v*)src;
    long q0 = (long)blockIdx.x * (EPB / 4), qend = q0 + EPB / 4;
    for (long qb = q0; qb < qend; qb += 256) {
        long q = qb + t;
        if (q < qend) {
            int4v d = __builtin_nontemporal_load(dst4 + q);
            int4v s = __builtin_nontemporal_load(src4 + q);
            #pragma unroll
            for (int u = 0; u < 4; ++u) {
                int dd = (u == 0) ? d.x : (u == 1) ? d.y : (u == 2) ? d.z : d.w;
                int ss = (u == 0) ? s.x : (u == 1) ? s.y : (u == 2) ? s.z : s.w;
                int b  = dd >> BSH;
                int pk = (ss << BSH) | (dd & (BSZ - 1));
                int pos = atomicAdd(&lcnt[b], 1);
                if (pos < CAP) fifo[b][pos] = pk;
                else { int p = atomicAdd(&gcur[b], 1); pairs[p] = pk; }  // rare spill
            }
        }
        __syncthreads();
        if (t < NBUCK) {
            int c = lcnt[t]; if (c > CAP) c = CAP;
            if (c > 0) {
                int base = atomicAdd(&gcur[t], c);
                for (int j = 0; j < c; ++j) pairs[base + j] = fifo[t][j];
                lcnt[t] = 0;
            }
        }
        __syncthreads();
    }
}

// per-bucket fine degree histogram in LDS -> degi
__global__ __launch_bounds__(256) void k_bdeg(const int* __restrict__ pairs,
                                              const int* __restrict__ bptr,
                                              int* __restrict__ degi) {
    __shared__ int cnt[BSZ];
    const int t = threadIdx.x;
    const int k = blockIdx.x >> 3, j = blockIdx.x & 7;
    for (int i = t; i < BSZ; i += 256) cnt[i] = 0;
    __syncthreads();
    int p0 = bptr[k], len = bptr[k + 1] - p0;
    int s0 = p0 + (int)((long)len * j / 8);
    int s1 = p0 + (int)((long)len * (j + 1) / 8);
    for (int i = s0 + t; i < s1; i += 256)
        atomicAdd(&cnt[pairs[i] & (BSZ - 1)], 1);
    __syncthreads();
    int base = k << BSH;
    for (int i = t; i < BSZ; i += 256) {
        int c = cnt[i];
        if (c > 0 && base + i < N) atomicAdd(&degi[base + i], c);
    }
}

// Pass A: per-1024-chunk totals
__global__ __launch_bounds__(256) void k_blocksum(const int* __restrict__ degi,
                                                  int* __restrict__ bsum) {
    const int t = threadIdx.x, b = blockIdx.x;
    long i0 = (long)b * 1024 + t * 4;
    int s = 0;
    #pragma unroll
    for (int u = 0; u < 4; ++u) { long i = i0 + u; if (i < N) s += degi[i]; }
    #pragma unroll
    for (int o = 32; o > 0; o >>= 1) s += __shfl_xor(s, o);
    __shared__ int ws_[4];
    int lane = t & 63, wid = t >> 6;
    if (lane == 0) ws_[wid] = s;
    __syncthreads();
    if (t == 0) bsum[b] = ws_[0] + ws_[1] + ws_[2] + ws_[3];
}

// Pass B: exclusive scan of 98 block totals (single block)
__global__ __launch_bounds__(128) void k_scanbsum(const int* __restrict__ bsum,
                                                  int* __restrict__ boff) {
    const int t = threadIdx.x;
    __shared__ int tmp[128];
    int v = (t < NB) ? bsum[t] : 0;
    tmp[t] = v;
    __syncthreads();
    for (int o = 1; o < 128; o <<= 1) {
        int y = (t >= o) ? tmp[t - o] : 0;
        __syncthreads();
        tmp[t] += y;
        __syncthreads();
    }
    if (t < NB) boff[t] = tmp[t] - v;   // exclusive
}

// Pass C: final exclusive scan -> rowptr, fillcur
__global__ __launch_bounds__(256) void k_scanfinal(const int* __restrict__ degi,
                                                   const int* __restrict__ boff,
                                                   int* __restrict__ rowptr,
                                                   int* __restrict__ fillcur) {
    const int t = threadIdx.x, b = blockIdx.x;
    const int lane = t & 63, wid = t >> 6;
    long i0 = (long)b * 1024 + t * 4;
    int d[4];
    #pragma unroll
    for (int u = 0; u < 4; ++u) { long i = i0 + u; d[u] = (i < N) ? degi[i] : 0; }
    int tsum = d[0] + d[1] + d[2] + d[3];
    int incl = tsum;
    #pragma unroll
    for (int o = 1; o < 64; o <<= 1) {
        int y = __shfl_up(incl, o);
        if (lane >= o) incl += y;
    }
    __shared__ int wsum[4];
    if (lane == 63) wsum[wid] = incl;
    __syncthreads();
    int wbase = 0;
    for (int w = 0; w < 4; ++w) if (w < wid) wbase += wsum[w];
    int base = boff[b] + wbase + (incl - tsum);
    int run = base;
    #pragma unroll
    for (int u = 0; u < 4; ++u) {
        long i = i0 + u;
        if (i < N) { rowptr[i] = run; fillcur[i] = run; }
        run += d[u];
    }
}

__global__ __launch_bounds__(256) void k_dinv(const int* __restrict__ degi,
                                              float* __restrict__ dinv) {
    int i = blockIdx.x * blockDim.x + threadIdx.x;
    if (i < N) dinv[i] = rsqrtf((float)degi[i] + 1.0f);   // +1 self loop
}

// per-bucket CSR fill from pairs; phased grid (8 groups x 32 slices) keeps
// each XCD's live windows ~2 MB
__global__ __launch_bounds__(256) void k_bucketfill(const int* __restrict__ pairs,
                                                    const int* __restrict__ bptr,
                                                    int* __restrict__ fillcur,
                                                    int* __restrict__ colidx) {
    const int t  = threadIdx.x;
    const int G  = blockIdx.x >> 5;   // 0..7
    const int sl = blockIdx.x & 31;   // 0..31
    for (int ph = 0; ph < 7; ++ph) {
        int k = G + 8 * ph;
        if (k >= NBUCK) break;
        int p0 = bptr[k], len = bptr[k + 1] - p0;
        int s0 = p0 + (int)((long)len * sl / 32);
        int s1 = p0 + (int)((long)len * (sl + 1) / 32);
        int base = k << BSH;
        for (int i = s0 + t; i < s1; i += 256) {
            int pk  = pairs[i];
            int d   = base + (pk & (BSZ - 1));
            int pos = atomicAdd(&fillcur[d], 1);
            colidx[pos] = pk >> BSH;
        }
    }
}

// ---------------- compute ----------------

// h1[i][j] = dinv[i] * sum_k x[i][k] * W1[k][j], stored fp16 padded to 64
__global__ __launch_bounds__(256, 2) void k_gemm1(const float* __restrict__ x,
                                                  const float* __restrict__ W1,
                                                  const float* __restrict__ dinv,
                                                  __half* __restrict__ h1) {
    __shared__ float xs[64][XS_LD];     // 33 KB, padded vs bank conflicts
    __shared__ float Ws[F_IN][WS_LD];   // 32 KB, j padded to 64
    const int t = threadIdx.x;
    const int row0 = blockIdx.x * 64;

    for (int i = t; i < F_IN * H; i += 256)
        Ws[i / H][i % H] = W1[i];
    for (int i = t; i < F_IN * (WS_LD - H); i += 256)
        Ws[i / (WS_LD - H)][H + i % (WS_LD - H)] = 0.0f;
    for (int i = t; i < 64 * (F_IN / 4); i += 256) {
        int r  = i >> 5;
        int c4 = i & 31;
        int gr = row0 + r;
        float4 v = make_float4(0.f, 0.f, 0.f, 0.f);
        if (gr < N) v = *(const float4*)(x + (long)gr * F_IN + c4 * 4);
        *(float4*)&xs[r][c4 * 4] = v;
    }
    __syncthreads();

    const int r  = t >> 2;
    const int g  = t & 3;
    const int j0 = g * 16;
    float acc[16];
    #pragma unroll
    for (int u = 0; u < 16; ++u) acc[u] = 0.0f;

    const float* xrow = &xs[r][0];
    #pragma unroll 4
    for (int k0 = 0; k0 < F_IN; k0 += 4) {
        float4 xv = *(const float4*)(xrow + k0);
        float xk[4] = {xv.x, xv.y, xv.z, xv.w};
        #pragma unroll
        for (int kk = 0; kk < 4; ++kk) {
            const float* wrow = &Ws[k0 + kk][j0];
            float4 wa = *(const float4*)(wrow);
            float4 wb = *(const float4*)(wrow + 4);
            float4 wc = *(const float4*)(wrow + 8);
            float4 wd = *(const float4*)(wrow + 12);
            float xr = xk[kk];
            acc[0]  += xr * wa.x; acc[1]  += xr * wa.y;
            acc[2]  += xr * wa.z; acc[3]  += xr * wa.w;
            acc[4]  += xr * wb.x; acc[5]  += xr * wb.y;
            acc[6]  += xr * wb.z; acc[7]  += xr * wb.w;
            acc[8]  += xr * wc.x; acc[9]  += xr * wc.y;
            acc[10] += xr * wc.z; acc[11] += xr * wc.w;
            acc[12] += xr * wd.x; acc[13] += xr * wd.y;
            acc[14] += xr * wd.z; acc[15] += xr * wd.w;
        }
    }

    int gr = row0 + r;
    if (gr >= N) return;
    float di = dinv[gr];
    __half* hrow = h1 + (long)gr * HP + j0;
    #pragma unroll
    for (int u = 0; u < 16; u += 2) {
        int j = j0 + u;
        if (j < H) {
            __half2 hv;
            hv.x = __float2half(di * acc[u]);
            hv.y = (j + 1 < H) ? __float2half(di * acc[u + 1]) : __half(0);
            *(__half2*)(hrow + u) = hv;
        }
    }
}

// wave-per-node: agg1 = self + sum_{nbr} h1[nbr]; z1 = relu(di*agg1+b1);
// h2[i] = di * (z1 @ W2).  h1 fp16, rows 128 B (2 lines) each.
__global__ __launch_bounds__(256) void k_agg1_fused(const int* __restrict__ rowptr,
                                                    const int* __restrict__ degi,
                                                    const int* __restrict__ colidx,
                                                    const __half* __restrict__ h1,
                                                    const float* __restrict__ dinv,
                                                    const float* __restrict__ b1,
                                                    const float* __restrict__ W2,
                                                    float* __restrict__ h2) {
    const int lane = threadIdx.x & 63;
    const bool act = lane < H;
    float b1v = act ? b1[lane] : 0.0f;
    float w20 = act ? W2[lane * 2 + 0] : 0.0f;
    float w21 = act ? W2[lane * 2 + 1] : 0.0f;

    long gw = ((long)blockIdx.x * blockDim.x + threadIdx.x) >> 6;
    long nw = ((long)gridDim.x * blockDim.x) >> 6;
    for (long i = gw; i < N; i += nw) {
        const int start = rowptr[i];
        const int deg   = degi[i];
        float a0 = act ? __half2float(h1[i * (long)HP + lane]) : 0.0f;  // self
        float a1 = 0.0f, a2 = 0.0f, a3 = 0.0f;
        int k = 0;
        for (; k + 4 <= deg; k += 4) {
            int s0 = colidx[start + k + 0];
            int s1 = colidx[start + k + 1];
            int s2 = colidx[start + k + 2];
            int s3 = colidx[start + k + 3];
            if (act) {
                a0 += __half2float(h1[(long)s0 * HP + lane]);
                a1 += __half2float(h1[(long)s1 * HP + lane]);
                a2 += __half2float(h1[(long)s2 * HP + lane]);
                a3 += __half2float(h1[(long)s3 * HP + lane]);
            }
        }
        for (; k < deg; ++k) {
            int s = colidx[start + k];
            if (act) a0 += __half2float(h1[(long)s * HP + lane]);
        }
        float agg = (a0 + a1) + (a2 + a3);
        float di = dinv[i];
        float v = fmaxf(di * agg + b1v, 0.0f);
        float p0 = v * w20, p1 = v * w21;
        #pragma unroll
        for (int o = 32; o > 0; o >>= 1) {
            p0 += __shfl_xor(p0, o);
            p1 += __shfl_xor(p1, o);
        }
        if (lane == 0) {
            h2[i * 2 + 0] = di * p0;
            h2[i * 2 + 1] = di * p1;
        }
    }
}

// wave-per-node, lanes over edges: out = log_softmax(di*(sum+self)+b2)
__global__ __launch_bounds__(256) void k_agg2_final(const int* __restrict__ rowptr,
                                                    const int* __restrict__ degi,
                                                    const int* __restrict__ colidx,
                                                    const float* __restrict__ h2,
                                                    const float* __restrict__ dinv,
                                                    const float* __restrict__ b2,
                                                    float* __restrict__ out) {
    const int lane = threadIdx.x & 63;
    long gw = ((long)blockIdx.x * blockDim.x + threadIdx.x) >> 6;
    long nw = ((long)gridDim.x * blockDim.x) >> 6;
    for (long i = gw; i < N; i += nw) {
        const int start = rowptr[i];
        const int deg   = degi[i];
        float s0 = 0.0f, s1 = 0.0f;
        for (int k = lane; k < deg; k += 64) {
            int s = colidx[start + k];
            s0 += h2[(long)s * 2 + 0];
            s1 += h2[(long)s * 2 + 1];
        }
        #pragma unroll
        for (int o = 32; o > 0; o >>= 1) {
            s0 += __shfl_xor(s0, o);
            s1 += __shfl_xor(s1, o);
        }
        if (lane == 0) {
            float di = dinv[i];
            float a0 = di * (s0 + h2[i * 2 + 0]) + b2[0];
            float a1 = di * (s1 + h2[i * 2 + 1]) + b2[1];
            float m = fmaxf(a0, a1);
            float lse = m + logf(expf(a0 - m) + expf(a1 - m));
            out[i * 2 + 0] = a0 - lse;
            out[i * 2 + 1] = a1 - lse;
        }
    }
}

extern "C" void kernel_launch(void* const* d_in, const int* in_sizes, int n_in,
                              void* d_out, int out_size, void* d_ws, size_t ws_size,
                              hipStream_t stream) {
    const float* x  = (const float*)d_in[0];
    const int*   ei = (const int*)d_in[1];   // [2][E]: row0 src, row1 dst
    const float* W1 = (const float*)d_in[2];
    const float* b1 = (const float*)d_in[3];
    const float* W2 = (const float*)d_in[4];
    const float* b2 = (const float*)d_in[5];
    float* out = (float*)d_out;

    const int* src = ei;
    const int* dst = ei + E;

    // ws layout
    int*    degi    = (int*)d_ws;            // N
    int*    rowptr  = degi + N;              // N
    int*    fillcur = rowptr + N;            // N
    int*    bsum    = fillcur + N;           // 128
    int*    boff    = bsum + 128;            // 128
    int*    bcnt    = boff + 128;            // 64
    int*    bptr    = bcnt + 64;             // 80 (needs 50)
    int*    gcur    = bptr + 80;             // 64
    float*  dinv    = (float*)(gcur + 64);   // N
    int*    pairs   = (int*)(dinv + N);      // E
    int*    colidx  = pairs + E;             // E
    __half* h1      = (__half*)(colidx + E); // N*64 halves (12.8 MB)
    float*  h2      = (float*)(h1 + (long)N * HP);  // N*C  (~41 MB total)

    k_zero<<<(N + 255) / 256, 256, 0, stream>>>(degi, bcnt);
    k_coarse<<<PART_NBLK, 256, 0, stream>>>(dst, bcnt);
    k_scan49<<<1, 64, 0, stream>>>(bcnt, bptr, gcur);
    k_part<<<PART_NBLK, 256, 0, stream>>>(src, dst, gcur, pairs);
    k_bdeg<<<NBUCK * 8, 256, 0, stream>>>(pairs, bptr, degi);
    k_dinv<<<(N + 255) / 256, 256, 0, stream>>>(degi, dinv);
    k_blocksum<<<NB, 256, 0, stream>>>(degi, bsum);
    k_scanbsum<<<1, 128, 0, stream>>>(bsum, boff);
    k_scanfinal<<<NB, 256, 0, stream>>>(degi, boff, rowptr, fillcur);
    k_bucketfill<<<256, 256, 0, stream>>>(pairs, bptr, fillcur, colidx);
    k_gemm1<<<(N + 63) / 64, 256, 0, stream>>>(x, W1, dinv, h1);
    k_agg1_fused<<<2048, 256, 0, stream>>>(rowptr, degi, colidx, h1, dinv, b1, W2, h2);
    k_agg2_final<<<2048, 256, 0, stream>>>(rowptr, degi, colidx, h2, dinv, b2, out);
}